// Round 14
// baseline (95.451 us; speedup 1.0000x reference)
//
#include <hip/hip_runtime.h>
#include <math.h>

#define NJ 4         // odd powers x^1..x^7
#define DEG 7
#define X0f 1.1f     // poly valid on [-1.1,1.1]; typical |s*g| ~ 0.4
#define ESTR 464     // wsEnc row stride (456 data + 8 zero pad floats)

struct Poly { float c[NJ]; };

typedef float v4f __attribute__((ext_vector_type(4)));

// ---------------- K0: repack weights ----------------
// WcT[i][m 0..463][32]; W1T[m 0..455][128]; Wt0[304][152], Wt1[76][152], Wt2[36][152]
__global__ __launch_bounds__(256) void k_repack(
    const float* __restrict__ Wc, const float* __restrict__ W1,
    const float* __restrict__ eW0, const float* __restrict__ eW1, const float* __restrict__ eW2,
    float* __restrict__ WcT, float* __restrict__ W1T,
    float* __restrict__ Wt0, float* __restrict__ Wt1, float* __restrict__ Wt2) {
    int tid = blockIdx.x * 256 + threadIdx.x;
    int stride = gridDim.x * 256;
    for (int idx = tid; idx < 3 * 464 * 32; idx += stride) {
        int i = idx / (464 * 32); int rem = idx - i * 464 * 32;
        int m = rem >> 5, h = rem & 31;
        float v = 0.f;
        if (m < 456) {
            int seg = m / 152, e = m - seg * 152;
            if (e < 150) v = Wc[((size_t)i * 32 + h) * 450 + seg * 150 + e];
        }
        WcT[idx] = v;
    }
    for (int idx = tid; idx < 456 * 128; idx += stride) {
        int m = idx >> 7, k = idx & 127;
        int seg = m / 152, e = m - seg * 152;
        W1T[idx] = (e < 150) ? W1[k * 450 + seg * 150 + e] : 0.f;
    }
    for (int idx = tid; idx < 304 * 152; idx += stride) {
        int d = idx / 152, e = idx - d * 152;
        Wt0[idx] = (d < 300 && e < 150) ? eW0[e * 300 + d] : 0.f;
    }
    for (int idx = tid; idx < 76 * 152; idx += stride) {
        int d = idx / 152, e = idx - d * 152;
        Wt1[idx] = (d < 74 && e < 150) ? eW1[e * 74 + d] : 0.f;
    }
    for (int idx = tid; idx < 36 * 152; idx += stride) {
        int d = idx / 152, e = idx - d * 152;
        Wt2[idx] = (d < 35 && e < 150) ? eW2[e * 35 + d] : 0.f;
    }
}

// ---------------- K1: encoders. grid 512 (4 rows/block), block 256, no LDS/barriers ----------------
__global__ __launch_bounds__(256) void k_enc(
    const float* __restrict__ x0, const float* __restrict__ x1, const float* __restrict__ x2,
    const float* __restrict__ eb0, const float* __restrict__ eb1, const float* __restrict__ eb2,
    const float* __restrict__ Wt0, const float* __restrict__ Wt1, const float* __restrict__ Wt2,
    float* __restrict__ wsEnc) {
#pragma clang fp contract(fast)
    int tid = threadIdx.x;
    int b0 = blockIdx.x * 4;
    if (tid < 32) {   // zero the 8-float row pads (m4 = 114,115)
        int b = tid >> 3, j = tid & 7;
        wsEnc[(size_t)(b0 + b) * ESTR + 456 + j] = 0.f;
    }
    for (int task = tid; task < 456; task += 256) {
        int b = task & 3, m4 = task >> 2;
        int row = b0 + b;
        int seg = (m4 >= 76) ? 2 : (m4 >= 38) ? 1 : 0;
        int e4 = m4 - seg * 38;
        int e = e4 * 4;
        const float* eb = seg == 0 ? eb0 : seg == 1 ? eb1 : eb2;
        v4f acc = { (e < 150) ? eb[e] : 0.f,
                    (e + 1 < 150) ? eb[e + 1] : 0.f,
                    (e + 2 < 150) ? eb[e + 2] : 0.f,
                    (e + 3 < 150) ? eb[e + 3] : 0.f };
        if (seg == 0) {
            const v4f* W4 = (const v4f*)Wt0 + e4;
            const v4f* xr = (const v4f*)(x0 + (size_t)row * 300);  // 1200B rows: aligned
            for (int d4 = 0; d4 < 75; ++d4) {
                v4f x4 = xr[d4];
                v4f w0 = W4[(d4 * 4 + 0) * 38];
                v4f w1 = W4[(d4 * 4 + 1) * 38];
                v4f w2 = W4[(d4 * 4 + 2) * 38];
                v4f w3 = W4[(d4 * 4 + 3) * 38];
                acc += x4.x * w0;
                acc += x4.y * w1;
                acc += x4.z * w2;
                acc += x4.w * w3;
            }
        } else if (seg == 1) {
            const v4f* W4 = (const v4f*)Wt1 + e4;
            const float* xb = x1 + (size_t)row * 74;   // odd rows misaligned: scalar x
            #pragma unroll 2
            for (int d = 0; d < 74; ++d) acc += xb[d] * W4[d * 38];
        } else {
            const v4f* W4 = (const v4f*)Wt2 + e4;
            const float* xb = x2 + (size_t)row * 35;
            #pragma unroll 5
            for (int d = 0; d < 35; ++d) acc += xb[d] * W4[d * 38];
        }
        ((v4f*)(wsEnc + (size_t)row * ESTR))[m4] = acc;
    }
}

// ---------------- K2: attention. grid (1024 pairs, 3 branches), block 64 = 1 wave, no LDS ----------------
__global__ __launch_bounds__(64) void k_attn(
    const float* __restrict__ wsEnc,
    const float* __restrict__ WcT,
    const float* __restrict__ affw, const float* __restrict__ Ww, const float* __restrict__ Wh,
    float* __restrict__ fof, Poly pc) {
#pragma clang fp contract(fast)
    int lane = threadIdx.x;
    int i = blockIdx.y;
    int bA = blockIdx.x * 2, bB = bA + 1;
    int hq = lane & 7, slice = lane >> 3;          // M-phase roles
    int slice2 = (lane >> 3) & 3, bh = lane >> 5;  // epilogue roles
    float aff = affw[i];
    const v4f* Wb4 = (const v4f*)WcT + (size_t)i * 3712 + hq;
    const v4f* frowA = (const v4f*)(wsEnc + (size_t)bA * ESTR);
    const v4f* frowB = (const v4f*)(wsEnc + (size_t)bB * ESTR);

    v4f accA[NJ], accB[NJ];
    #pragma unroll
    for (int J = 0; J < NJ; ++J) { accA[J] = (v4f)0.f; accB[J] = (v4f)0.f; }
    float mxA = 0.f, mxB = 0.f;

    int m4lo = (slice < 4) ? slice * 15 : 60 + (slice - 4) * 14;
    int m4n  = (slice < 4) ? 15 : 14;
    #pragma unroll 3
    for (int k = 0; k < m4n; ++k) {
        int m4 = m4lo + k;
        v4f fA = frowA[m4];
        v4f fB = frowB[m4];
        const v4f* wp4 = Wb4 + m4 * 32;
        v4f w0 = wp4[0];
        v4f w1 = wp4[8];
        v4f w2 = wp4[16];
        v4f w3 = wp4[24];
        mxA = fmaxf(mxA, fmaxf(fmaxf(fabsf(fA.x), fabsf(fA.y)), fmaxf(fabsf(fA.z), fabsf(fA.w))));
        mxB = fmaxf(mxB, fmaxf(fmaxf(fabsf(fB.x), fabsf(fB.y)), fmaxf(fabsf(fB.z), fabsf(fB.w))));
        {
            float g0 = aff * fA.x, g1 = aff * fA.y, g2 = aff * fA.z, g3 = aff * fA.w;
            float q0 = g0 * g0, q1 = g1 * g1, q2 = g2 * g2, q3 = g3 * g3;
            float p0 = g0, p1 = g1, p2 = g2, p3 = g3;
            accA[0] += p0 * w0; accA[0] += p1 * w1; accA[0] += p2 * w2; accA[0] += p3 * w3;
            #pragma unroll
            for (int J = 1; J < NJ; ++J) {
                p0 *= q0; p1 *= q1; p2 *= q2; p3 *= q3;
                accA[J] += p0 * w0; accA[J] += p1 * w1; accA[J] += p2 * w2; accA[J] += p3 * w3;
            }
        }
        {
            float g0 = aff * fB.x, g1 = aff * fB.y, g2 = aff * fB.z, g3 = aff * fB.w;
            float q0 = g0 * g0, q1 = g1 * g1, q2 = g2 * g2, q3 = g3 * g3;
            float p0 = g0, p1 = g1, p2 = g2, p3 = g3;
            accB[0] += p0 * w0; accB[0] += p1 * w1; accB[0] += p2 * w2; accB[0] += p3 * w3;
            #pragma unroll
            for (int J = 1; J < NJ; ++J) {
                p0 *= q0; p1 *= q1; p2 *= q2; p3 *= q3;
                accB[J] += p0 * w0; accB[J] += p1 * w1; accB[J] += p2 * w2; accB[J] += p3 * w3;
            }
        }
    }
    // reduce partial M across slice bits (8,16,32), fold poly coeff
    #pragma unroll
    for (int J = 0; J < NJ; ++J) {
        float cJ = pc.c[J];
        float vx, vy, vz, vw;
        vx = accA[J].x; vx += __shfl_xor(vx, 8); vx += __shfl_xor(vx, 16); vx += __shfl_xor(vx, 32);
        vy = accA[J].y; vy += __shfl_xor(vy, 8); vy += __shfl_xor(vy, 16); vy += __shfl_xor(vy, 32);
        vz = accA[J].z; vz += __shfl_xor(vz, 8); vz += __shfl_xor(vz, 16); vz += __shfl_xor(vz, 32);
        vw = accA[J].w; vw += __shfl_xor(vw, 8); vw += __shfl_xor(vw, 16); vw += __shfl_xor(vw, 32);
        accA[J] = (v4f){ vx * cJ, vy * cJ, vz * cJ, vw * cJ };
        vx = accB[J].x; vx += __shfl_xor(vx, 8); vx += __shfl_xor(vx, 16); vx += __shfl_xor(vx, 32);
        vy = accB[J].y; vy += __shfl_xor(vy, 8); vy += __shfl_xor(vy, 16); vy += __shfl_xor(vy, 32);
        vz = accB[J].z; vz += __shfl_xor(vz, 8); vz += __shfl_xor(vz, 16); vz += __shfl_xor(vz, 32);
        vw = accB[J].w; vw += __shfl_xor(vw, 8); vw += __shfl_xor(vw, 16); vw += __shfl_xor(vw, 32);
        accB[J] = (v4f){ vx * cJ, vy * cJ, vz * cJ, vw * cJ };
    }
    mxA = fmaxf(mxA, __shfl_xor(mxA, 8));
    mxA = fmaxf(mxA, __shfl_xor(mxA, 16));
    mxA = fmaxf(mxA, __shfl_xor(mxA, 32));
    mxB = fmaxf(mxB, __shfl_xor(mxB, 8));
    mxB = fmaxf(mxB, __shfl_xor(mxB, 16));
    mxB = fmaxf(mxB, __shfl_xor(mxB, 32));

    // select this lane's epilogue row (static J indexing)
    v4f Ms[NJ];
    #pragma unroll
    for (int J = 0; J < NJ; ++J) Ms[J] = bh ? accB[J] : accA[J];
    float gmax = fabsf(aff) * (bh ? mxB : mxA);
    int b = bA + bh;
    const float* fb = wsEnc + (size_t)b * ESTR;
    const v4f* frow = bh ? frowB : frowA;

    v4f wW4 = ((const v4f*)(Ww + i * 32))[hq];
    v4f wH4 = ((const v4f*)(Wh + i * 32))[hq];
    int e4lo = slice2 * 10;
    int e4hi = (slice2 == 3) ? 38 : (e4lo + 10);
    for (int e4 = e4lo; e4 < e4hi; ++e4) {
        v4f s4 = frow[i * 38 + e4];
        float ores[4];
        #pragma unroll
        for (int r = 0; r < 4; ++r) {
            float s = (r == 0) ? s4.x : (r == 1) ? s4.y : (r == 2) ? s4.z : s4.w;
            v4f a4;
            if (fabsf(s) * gmax <= X0f) {
                float s2 = s * s, p = s;
                a4 = Ms[0] * p;
                #pragma unroll
                for (int J = 1; J < NJ; ++J) { p *= s2; a4 += p * Ms[J]; }
            } else {
                a4 = (v4f)0.f;
                for (int c = 0; c < 456; ++c) {
                    float t = tanhf(s * aff * fb[c]);
                    a4 += t * Wb4[(size_t)c * 8];
                }
            }
            v4f hv = s * wW4 + a4;
            hv = __builtin_elementwise_max(hv, (v4f)0.f);
            v4f dv = hv * wH4;
            float csum = dv.x + dv.y + dv.z + dv.w;
            csum += __shfl_xor(csum, 1);
            csum += __shfl_xor(csum, 2);
            csum += __shfl_xor(csum, 4);
            ores[r] = csum + s;
        }
        if (hq == 0)
            ((v4f*)(fof + (size_t)b * 456))[i * 38 + e4] = (v4f){ ores[0], ores[1], ores[2], ores[3] };
    }
}

// ---------------- K3: classifier. grid 512 (4 rows/block), block 256 ----------------
__global__ __launch_bounds__(256) void k_cls(
    const float* __restrict__ fof,
    const float* __restrict__ W1T, const float* __restrict__ cb1,
    const float* __restrict__ cW2, const float* __restrict__ cb2,
    float* __restrict__ out) {
#pragma clang fp contract(fast)
    __shared__ __align__(16) float clsP[2 * 4 * 32 * 4];  // [ch][b][kq] v4f
    __shared__ __align__(16) float hs[4][132];
    int tid = threadIdx.x;
    int b0 = blockIdx.x * 4;
    {
        int ch = tid >> 7;
        int rr = tid & 127;
        int b = rr & 3, kq = rr >> 2;
        const v4f* W14 = (const v4f*)W1T + kq;
        const v4f* fr = (const v4f*)(fof + (size_t)(b0 + b) * 456);
        v4f a = (v4f)0.f;
        int c4lo = ch * 57;
        for (int c4 = c4lo; c4 < c4lo + 57; ++c4) {
            v4f fv = fr[c4];
            v4f w0 = W14[(c4 * 4 + 0) * 32];
            v4f w1 = W14[(c4 * 4 + 1) * 32];
            v4f w2 = W14[(c4 * 4 + 2) * 32];
            v4f w3 = W14[(c4 * 4 + 3) * 32];
            a += fv.x * w0;
            a += fv.y * w1;
            a += fv.z * w2;
            a += fv.w * w3;
        }
        ((v4f*)clsP)[(ch * 4 + b) * 32 + kq] = a;
    }
    __syncthreads();
    if (tid < 128) {
        int b = tid >> 5, kq = tid & 31;
        v4f v = ((const v4f*)cb1)[kq];
        v += ((const v4f*)clsP)[(0 * 4 + b) * 32 + kq];
        v += ((const v4f*)clsP)[(1 * 4 + b) * 32 + kq];
        *((v4f*)&hs[b][kq * 4]) = v;
    }
    __syncthreads();
    if (tid < 28) {
        int b = tid / 7, o = tid - (tid / 7) * 7;
        const v4f* hb = (const v4f*)&hs[b][0];
        const v4f* w2 = (const v4f*)(cW2 + o * 128);
        v4f a4 = (v4f)0.f;
        #pragma unroll 8
        for (int k4 = 0; k4 < 32; ++k4) a4 += hb[k4] * w2[k4];
        out[(size_t)(b0 + b) * 7 + o] = cb2[o] + a4.x + a4.y + a4.z + a4.w;
    }
}

// ---------------- host: Chebyshev fit of tanh on [-1.1,1.1], odd monomials ----------------
static void make_poly(float* cf) {
    const double a = 1.1;
    const int NQ = 128;
    const double PI = 3.14159265358979323846;
    double b[DEG + 1];
    for (int k = 0; k <= DEG; ++k) b[k] = 0.0;
    for (int m = 0; m < NQ; ++m) {
        double th = PI * (m + 0.5) / NQ;
        double f = tanh(a * cos(th));
        for (int k = 1; k <= DEG; k += 2)
            b[k] += (2.0 / NQ) * f * cos(k * th);
    }
    double Tp[DEG + 1], Tc[DEG + 1], Tn[DEG + 1], mono[DEG + 1];
    for (int j = 0; j <= DEG; ++j) { Tp[j] = 0; Tc[j] = 0; mono[j] = 0; }
    Tp[0] = 1.0;
    Tc[1] = 1.0;
    for (int j = 0; j <= DEG; ++j) mono[j] += b[1] * Tc[j];
    for (int k = 2; k <= DEG; ++k) {
        for (int j = 0; j <= DEG; ++j) Tn[j] = -Tp[j];
        for (int j = 1; j <= DEG; ++j) Tn[j] += 2.0 * Tc[j - 1];
        for (int j = 0; j <= DEG; ++j) { Tp[j] = Tc[j]; Tc[j] = Tn[j]; }
        if (k & 1) for (int j = 0; j <= DEG; ++j) mono[j] += b[k] * Tc[j];
    }
    for (int J = 0; J < NJ; ++J) {
        int j = 2 * J + 1;
        cf[J] = (float)(mono[j] / pow(a, (double)j));
    }
}

extern "C" void kernel_launch(void* const* d_in, const int* in_sizes, int n_in,
                              void* d_out, int out_size, void* d_ws, size_t ws_size,
                              hipStream_t stream) {
    (void)in_sizes; (void)n_in; (void)out_size; (void)ws_size;
    const float* x0    = (const float*)d_in[0];
    const float* x1    = (const float*)d_in[1];
    const float* x2    = (const float*)d_in[2];
    const float* eW0   = (const float*)d_in[3];
    const float* eb0   = (const float*)d_in[4];
    const float* eW1   = (const float*)d_in[5];
    const float* eb1   = (const float*)d_in[6];
    const float* eW2   = (const float*)d_in[7];
    const float* eb2   = (const float*)d_in[8];
    const float* affw  = (const float*)d_in[9];
    const float* Ww    = (const float*)d_in[10];
    const float* Wc    = (const float*)d_in[11];
    const float* Wh    = (const float*)d_in[12];
    const float* cW1   = (const float*)d_in[13];
    const float* cb1   = (const float*)d_in[14];
    const float* cW2   = (const float*)d_in[15];
    const float* cb2   = (const float*)d_in[16];

    float* ws    = (float*)d_ws;
    float* wsWcT = ws;                  // 3*464*32  = 44544
    float* wsW1T = ws + 44544;          // 456*128   = 58368
    float* wsWt0 = ws + 102912;         // 304*152   = 46208
    float* wsWt1 = ws + 149120;         // 76*152    = 11552
    float* wsWt2 = ws + 160672;         // 36*152    = 5472
    float* wsEnc = ws + 166144;         // 2048*464  = 950272
    float* wsFof = ws + 1116416;        // 2048*456  = 933888

    Poly pc;
    make_poly(pc.c);

    k_repack<<<dim3(96), dim3(256), 0, stream>>>(Wc, cW1, eW0, eW1, eW2,
                                                 wsWcT, wsW1T, wsWt0, wsWt1, wsWt2);
    k_enc<<<dim3(512), dim3(256), 0, stream>>>(x0, x1, x2, eb0, eb1, eb2,
                                               wsWt0, wsWt1, wsWt2, wsEnc);
    k_attn<<<dim3(1024, 3), dim3(64), 0, stream>>>(wsEnc, wsWcT, affw, Ww, Wh, wsFof, pc);
    k_cls<<<dim3(512), dim3(256), 0, stream>>>(wsFof, wsW1T, cb1, cW2, cb2, (float*)d_out);
}